// Round 3
// baseline (205.581 us; speedup 1.0000x reference)
//
#include <hip/hip_runtime.h>
#include <hip/hip_bf16.h>

// out = (4096 * (x @ Wv)) @ w_proj + b_proj      [softmax rows sum to 1 =>
// head_w == N_NODES exactly; adj, w_q, w_k never affect the output]
// Wv[d][c=h*128+hd] = w_qkv[2][h][d][hd].  All global tensors fp32.
// Strategy: fold M = 4096*(Wv@Wp) once (bf16, in d_ws), then out = x@M + b.
// Both GEMMs on the bf16 MFMA pipe (16x16x32), fp32 accumulate.

constexpr int NNODES = 4096;
constexpr int DIM = 512;

typedef __bf16 bf16x8 __attribute__((ext_vector_type(8)));
typedef float f32x4 __attribute__((ext_vector_type(4)));

// LDS tiles: [row][k], k-stride padded 32->40 shorts (80 B: keeps ds_read_b128
// 16B-aligned, spreads banks).
#define KPAD 40

// ---------------------------------------------------------------------------
// Kernel A: M[d][o] = 4096 * sum_c Wv[d][c] * Wp[c][o], bf16 out.
// 64x64 tile, BK=32, 256 thr (4 waves), each wave 32x32 via 2x2 MFMA frags.
// ---------------------------------------------------------------------------
__global__ __launch_bounds__(256) void build_M(
    const float* __restrict__ w_qkv,
    const float* __restrict__ w_proj,
    __bf16* __restrict__ M) {
  __shared__ __bf16 as[64][KPAD];  // A: as[d_local][k]   (k contiguous)
  __shared__ __bf16 bs[64][KPAD];  // B: bs[o_local][k]   (LDS-transposed)
  const int d0 = blockIdx.y * 64, o0 = blockIdx.x * 64;
  const int tid = threadIdx.x;
  const int wave = tid >> 6, lane = tid & 63;
  const int ln = lane & 15, q = lane >> 4;
  const int wm = (wave >> 1) * 32, wn = (wave & 1) * 32;
  const float* __restrict__ wv = w_qkv + 2 * 4 * DIM * 128;  // v slice

  f32x4 acc[2][2] = {};

  for (int k0 = 0; k0 < DIM; k0 += 32) {
    const int h = k0 >> 7, hb = k0 & 127;
    // A tile: Wv rows d0..d0+63, k cols k0..k0+31 (inside one head block)
#pragma unroll
    for (int e = tid; e < 64 * 32; e += 256) {
      const int m = e >> 5, k = e & 31;
      as[m][k] = (__bf16)wv[(h * DIM + d0 + m) * 128 + hb + k];
    }
    // B tile: Wp rows k0..k0+31 (k), cols o0..o0+63 -> transpose into bs[o][k]
#pragma unroll
    for (int e = tid; e < 32 * 64; e += 256) {
      const int r = e >> 6, c = e & 63;  // r=k_local, c=o_local (coalesced read)
      bs[c][r] = (__bf16)w_proj[(k0 + r) * DIM + o0 + c];
    }
    __syncthreads();

    bf16x8 af[2], bf[2];
#pragma unroll
    for (int mi = 0; mi < 2; ++mi)
      af[mi] = *(const bf16x8*)&as[wm + mi * 16 + ln][q * 8];
#pragma unroll
    for (int ni = 0; ni < 2; ++ni)
      bf[ni] = *(const bf16x8*)&bs[wn + ni * 16 + ln][q * 8];
#pragma unroll
    for (int mi = 0; mi < 2; ++mi)
#pragma unroll
      for (int ni = 0; ni < 2; ++ni)
        acc[mi][ni] = __builtin_amdgcn_mfma_f32_16x16x32_bf16(
            af[mi], bf[ni], acc[mi][ni], 0, 0, 0);
    __syncthreads();
  }

  // C/D layout: col = lane&15, row = (lane>>4)*4 + reg
#pragma unroll
  for (int mi = 0; mi < 2; ++mi)
#pragma unroll
    for (int ni = 0; ni < 2; ++ni)
#pragma unroll
      for (int r = 0; r < 4; ++r) {
        const int row = d0 + wm + mi * 16 + q * 4 + r;   // d
        const int col = o0 + wn + ni * 16 + ln;          // o
        M[row * DIM + col] = (__bf16)(acc[mi][ni][r] * (float)NNODES);
      }
}

// ---------------------------------------------------------------------------
// Kernel B: out[b][o] = sum_d x[b][d] * M[d][o] + bias[o], fp32 out.
// Same tile structure; A = x (fp32 -> bf16 on staging), B = M (bf16,
// LDS-transposed into bs[o][k]).
// ---------------------------------------------------------------------------
__global__ __launch_bounds__(256) void gemm_out(
    const float* __restrict__ x,
    const __bf16* __restrict__ M,
    const float* __restrict__ bias,
    float* __restrict__ out) {
  __shared__ __bf16 as[64][KPAD];  // x tile [m][k]
  __shared__ __bf16 bs[64][KPAD];  // M tile transposed [n][k]
  const int bm = blockIdx.y * 64, bn = blockIdx.x * 64;
  const int tid = threadIdx.x;
  const int wave = tid >> 6, lane = tid & 63;
  const int ln = lane & 15, q = lane >> 4;
  const int wm = (wave >> 1) * 32, wn = (wave & 1) * 32;

  f32x4 acc[2][2] = {};

  for (int k0 = 0; k0 < DIM; k0 += 32) {
#pragma unroll
    for (int e = tid; e < 64 * 32; e += 256) {
      const int m = e >> 5, k = e & 31;
      as[m][k] = (__bf16)x[(bm + m) * DIM + k0 + k];
    }
#pragma unroll
    for (int e = tid; e < 32 * 64; e += 256) {
      const int r = e >> 6, c = e & 63;  // r=k_local, c=n_local (coalesced read)
      bs[c][r] = M[(k0 + r) * DIM + bn + c];
    }
    __syncthreads();

    bf16x8 af[2], bf[2];
#pragma unroll
    for (int mi = 0; mi < 2; ++mi)
      af[mi] = *(const bf16x8*)&as[wm + mi * 16 + ln][q * 8];
#pragma unroll
    for (int ni = 0; ni < 2; ++ni)
      bf[ni] = *(const bf16x8*)&bs[wn + ni * 16 + ln][q * 8];
#pragma unroll
    for (int mi = 0; mi < 2; ++mi)
#pragma unroll
      for (int ni = 0; ni < 2; ++ni)
        acc[mi][ni] = __builtin_amdgcn_mfma_f32_16x16x32_bf16(
            af[mi], bf[ni], acc[mi][ni], 0, 0, 0);
    __syncthreads();
  }

#pragma unroll
  for (int mi = 0; mi < 2; ++mi)
#pragma unroll
    for (int ni = 0; ni < 2; ++ni) {
      const int col = bn + wn + ni * 16 + ln;
      const float bj = bias[col];
#pragma unroll
      for (int r = 0; r < 4; ++r) {
        const int row = bm + wm + mi * 16 + q * 4 + r;
        out[row * DIM + col] = acc[mi][ni][r] + bj;
      }
    }
}

extern "C" void kernel_launch(void* const* d_in, const int* in_sizes, int n_in,
                              void* d_out, int out_size, void* d_ws, size_t ws_size,
                              hipStream_t stream) {
  const float* x      = (const float*)d_in[0];
  // d_in[1] = adj — irrelevant (softmax rows sum to 1), never read
  const float* w_qkv  = (const float*)d_in[2];
  const float* w_proj = (const float*)d_in[3];
  const float* b_proj = (const float*)d_in[4];
  __bf16* M = (__bf16*)d_ws;               // 512*512*2 = 512 KB scratch
  float* out = (float*)d_out;              // 4096*512 fp32

  build_M<<<dim3(DIM / 64, DIM / 64), 256, 0, stream>>>(w_qkv, w_proj, M);
  gemm_out<<<dim3(DIM / 64, NNODES / 64), 256, 0, stream>>>(x, M, b_proj, out);
}

// Round 4
// 129.747 us; speedup vs baseline: 1.5845x; 1.5845x over previous
//
#include <hip/hip_runtime.h>
#include <hip/hip_bf16.h>

// out = (4096 * (x @ Wv)) @ w_proj + b_proj   [softmax rows sum to 1 =>
// head_w == N_NODES exactly; adj, w_q, w_k never affect the output]
// Wv[d][c=h*128+hd] = w_qkv[2][h][d][hd].  All global tensors fp32.
//
// R4 design: both GEMMs are LDS-free direct-fragment MFMA kernels
// (no __syncthreads, no vmcnt(0) drains — pure load/MFMA pipelining).
// M is materialized TRANSPOSED (Mt[o][d], bf16) so gemm's B-fragments are
// 16B-contiguous global loads.

constexpr int NNODES = 4096;
constexpr int DIM = 512;

typedef __bf16 bf16x8 __attribute__((ext_vector_type(8)));
typedef float f32x4 __attribute__((ext_vector_type(4)));

__device__ __forceinline__ bf16x8 cvt8(const float* p) {
  const f32x4 lo = *(const f32x4*)p;
  const f32x4 hi = *(const f32x4*)(p + 4);
  bf16x8 r;
#pragma unroll
  for (int j = 0; j < 4; ++j) { r[j] = (__bf16)lo[j]; r[4 + j] = (__bf16)hi[j]; }
  return r;
}

// ---------------------------------------------------------------------------
// Kernel A: Mt[o][d] = 4096 * sum_c Wp[c][o] * Wv[d][c], bf16.
// One wave per 32(o) x 32(d) tile; A = Wp^T (column gather), B = Wv rows
// (contiguous fp32). Grid 16x16 = 256 single-wave blocks. No LDS.
// ---------------------------------------------------------------------------
__global__ __launch_bounds__(64) void build_Mt(
    const float* __restrict__ w_qkv,
    const float* __restrict__ w_proj,
    __bf16* __restrict__ Mt) {
  const int lane = threadIdx.x;
  const int ln = lane & 15, q = lane >> 4;
  const int m0 = blockIdx.y * 32;   // o rows of Mt
  const int n0 = blockIdx.x * 32;   // d cols of Mt
  const float* __restrict__ wv = w_qkv + 2 * 4 * DIM * 128;  // v slice

  f32x4 acc[2][2] = {};

#pragma unroll
  for (int k0 = 0; k0 < DIM; k0 += 32) {   // k = c (h*128+hd)
    const int h = k0 >> 7, hb = k0 & 127;
    bf16x8 af[2], bf[2];
    // A[m=o][k=c] = Wp[c][o]: per-lane gather of 8, 64B-coalesced across lanes
#pragma unroll
    for (int mi = 0; mi < 2; ++mi) {
      float raw[8];
#pragma unroll
      for (int j = 0; j < 8; ++j)
        raw[j] = w_proj[(k0 + q * 8 + j) * DIM + (m0 + mi * 16 + ln)];
#pragma unroll
      for (int j = 0; j < 8; ++j) af[mi][j] = (__bf16)raw[j];
    }
    // B[n=d][k=c] = Wv[d][c]: contiguous 32B fp32 per lane
#pragma unroll
    for (int ni = 0; ni < 2; ++ni)
      bf[ni] = cvt8(&wv[((size_t)h * DIM + (n0 + ni * 16 + ln)) * 128 + hb + q * 8]);
#pragma unroll
    for (int mi = 0; mi < 2; ++mi)
#pragma unroll
      for (int ni = 0; ni < 2; ++ni)
        acc[mi][ni] = __builtin_amdgcn_mfma_f32_16x16x32_bf16(
            af[mi], bf[ni], acc[mi][ni], 0, 0, 0);
  }

  // D layout: col = lane&15, row = (lane>>4)*4 + reg
#pragma unroll
  for (int mi = 0; mi < 2; ++mi)
#pragma unroll
    for (int ni = 0; ni < 2; ++ni)
#pragma unroll
      for (int r = 0; r < 4; ++r) {
        const int o = m0 + mi * 16 + q * 4 + r;
        const int d = n0 + ni * 16 + ln;
        Mt[o * DIM + d] = (__bf16)(acc[mi][ni][r] * (float)NNODES);
      }
}

// ---------------------------------------------------------------------------
// Kernel B: out[b][o] = sum_d x[b][d] * Mt[o][d] + bias[o], fp32 out.
// One wave per 32(b) x 64(o) tile. A-frags: x fp32 rows (2x dwordx4 + cvt);
// B-frags: Mt rows, one 16B load each. Grid 8 x 128 = 1024 single-wave blocks.
// ---------------------------------------------------------------------------
__global__ __launch_bounds__(64) void gemm_out(
    const float* __restrict__ x,
    const __bf16* __restrict__ Mt,
    const float* __restrict__ bias,
    float* __restrict__ out) {
  const int lane = threadIdx.x;
  const int ln = lane & 15, q = lane >> 4;
  const int m0 = blockIdx.y * 32;   // b rows
  const int n0 = blockIdx.x * 64;   // o cols

  f32x4 acc[2][4] = {};

#pragma unroll 4
  for (int k0 = 0; k0 < DIM; k0 += 32) {
    bf16x8 af[2], bf[4];
#pragma unroll
    for (int mi = 0; mi < 2; ++mi)
      af[mi] = cvt8(&x[(size_t)(m0 + mi * 16 + ln) * DIM + k0 + q * 8]);
#pragma unroll
    for (int ni = 0; ni < 4; ++ni)
      bf[ni] = *(const bf16x8*)&Mt[(size_t)(n0 + ni * 16 + ln) * DIM + k0 + q * 8];
#pragma unroll
    for (int mi = 0; mi < 2; ++mi)
#pragma unroll
      for (int ni = 0; ni < 4; ++ni)
        acc[mi][ni] = __builtin_amdgcn_mfma_f32_16x16x32_bf16(
            af[mi], bf[ni], acc[mi][ni], 0, 0, 0);
  }

#pragma unroll
  for (int ni = 0; ni < 4; ++ni) {
    const int o = n0 + ni * 16 + ln;
    const float bj = bias[o];
#pragma unroll
    for (int mi = 0; mi < 2; ++mi)
#pragma unroll
      for (int r = 0; r < 4; ++r) {
        const int b = m0 + mi * 16 + q * 4 + r;
        out[(size_t)b * DIM + o] = acc[mi][ni][r] + bj;
      }
  }
}

extern "C" void kernel_launch(void* const* d_in, const int* in_sizes, int n_in,
                              void* d_out, int out_size, void* d_ws, size_t ws_size,
                              hipStream_t stream) {
  const float* x      = (const float*)d_in[0];
  // d_in[1] = adj — irrelevant (softmax rows sum to 1), never read
  const float* w_qkv  = (const float*)d_in[2];
  const float* w_proj = (const float*)d_in[3];
  const float* b_proj = (const float*)d_in[4];
  __bf16* Mt = (__bf16*)d_ws;              // 512*512*2 = 512 KB scratch
  float* out = (float*)d_out;              // 4096*512 fp32

  build_Mt<<<dim3(DIM / 32, DIM / 32), 64, 0, stream>>>(w_qkv, w_proj, Mt);
  gemm_out<<<dim3(DIM / 64, NNODES / 32), 64, 0, stream>>>(x, Mt, b_proj, out);
}

// Round 5
// 125.819 us; speedup vs baseline: 1.6339x; 1.0312x over previous
//
#include <hip/hip_runtime.h>
#include <hip/hip_bf16.h>

// out = (4096 * (x @ Wv)) @ w_proj + b_proj   [softmax rows sum to 1 =>
// head_w == N_NODES exactly; adj, w_q, w_k never affect the output]
// Wv[d][c=h*128+hd] = w_qkv[2][h][d][hd].  All global tensors fp32.
//
// R5: three LDS-free MFMA/stream kernels.
//  1) cvt_x: x fp32 -> xb bf16 (once) so gemm A-frags are single 16B loads.
//  2) build_Mt: Mt[o][d] = 4096 * (Wv@Wp)^T, bf16 (validated in R4).
//  3) gemm_out: out = xb @ Mt^T + b; 4-wave blocks, 64x128 tile, 6 loads :
//     8 MFMAs per wave K-iter, no per-iter cvt.
// Fixed ~55us of harness poison/restore (256MB d_ws fill) dominates dur_us.

constexpr int NNODES = 4096;
constexpr int DIM = 512;

typedef __bf16 bf16x8 __attribute__((ext_vector_type(8)));
typedef float f32x4 __attribute__((ext_vector_type(4)));

__device__ __forceinline__ bf16x8 cvt8(const float* p) {
  const f32x4 lo = *(const f32x4*)p;
  const f32x4 hi = *(const f32x4*)(p + 4);
  bf16x8 r;
#pragma unroll
  for (int j = 0; j < 4; ++j) { r[j] = (__bf16)lo[j]; r[4 + j] = (__bf16)hi[j]; }
  return r;
}

// ---------------------------------------------------------------------------
// Kernel 0: xb = (bf16)x, 8 elems/thread.
// ---------------------------------------------------------------------------
__global__ __launch_bounds__(256) void cvt_x(
    const float* __restrict__ x, __bf16* __restrict__ xb) {
  const int t = blockIdx.x * 256 + threadIdx.x;
  *(bf16x8*)&xb[(size_t)t * 8] = cvt8(&x[(size_t)t * 8]);
}

// ---------------------------------------------------------------------------
// Kernel 1: Mt[o][d] = 4096 * sum_c Wp[c][o] * Wv[d][c], bf16.
// One wave per 32(o) x 32(d) tile. Grid 16x16 = 256 single-wave blocks.
// ---------------------------------------------------------------------------
__global__ __launch_bounds__(64) void build_Mt(
    const float* __restrict__ w_qkv,
    const float* __restrict__ w_proj,
    __bf16* __restrict__ Mt) {
  const int lane = threadIdx.x;
  const int ln = lane & 15, q = lane >> 4;
  const int m0 = blockIdx.y * 32;   // o rows of Mt
  const int n0 = blockIdx.x * 32;   // d cols of Mt
  const float* __restrict__ wv = w_qkv + 2 * 4 * DIM * 128;  // v slice

  f32x4 acc[2][2] = {};

#pragma unroll
  for (int k0 = 0; k0 < DIM; k0 += 32) {   // k = c (h*128+hd)
    const int h = k0 >> 7, hb = k0 & 127;
    bf16x8 af[2], bf[2];
#pragma unroll
    for (int mi = 0; mi < 2; ++mi) {
      float raw[8];
#pragma unroll
      for (int j = 0; j < 8; ++j)
        raw[j] = w_proj[(k0 + q * 8 + j) * DIM + (m0 + mi * 16 + ln)];
#pragma unroll
      for (int j = 0; j < 8; ++j) af[mi][j] = (__bf16)raw[j];
    }
#pragma unroll
    for (int ni = 0; ni < 2; ++ni)
      bf[ni] = cvt8(&wv[((size_t)h * DIM + (n0 + ni * 16 + ln)) * 128 + hb + q * 8]);
#pragma unroll
    for (int mi = 0; mi < 2; ++mi)
#pragma unroll
      for (int ni = 0; ni < 2; ++ni)
        acc[mi][ni] = __builtin_amdgcn_mfma_f32_16x16x32_bf16(
            af[mi], bf[ni], acc[mi][ni], 0, 0, 0);
  }

#pragma unroll
  for (int mi = 0; mi < 2; ++mi)
#pragma unroll
    for (int ni = 0; ni < 2; ++ni)
#pragma unroll
      for (int r = 0; r < 4; ++r) {
        const int o = m0 + mi * 16 + q * 4 + r;
        const int d = n0 + ni * 16 + ln;
        Mt[o * DIM + d] = (__bf16)(acc[mi][ni][r] * (float)NNODES);
      }
}

// ---------------------------------------------------------------------------
// Kernel 2: out[b][o] = sum_d xb[b][d] * Mt[o][d] + bias[o], fp32 out.
// 256 threads = 4 waves (2m x 2n); wave tile 32(b) x 64(o); block 64x128.
// Grid (512/128) x (4096/64) = 4 x 64 = 256 blocks, 8 waves/CU.
// Per wave K-iter: 2 + 4 = 6 x 16B loads, 8 MFMAs, zero cvt.
// ---------------------------------------------------------------------------
__global__ __launch_bounds__(256) void gemm_out(
    const __bf16* __restrict__ xb,
    const __bf16* __restrict__ Mt,
    const float* __restrict__ bias,
    float* __restrict__ out) {
  const int tid = threadIdx.x;
  const int wave = tid >> 6, lane = tid & 63;
  const int ln = lane & 15, q = lane >> 4;
  const int m0 = blockIdx.y * 64 + (wave >> 1) * 32;   // b rows
  const int n0 = blockIdx.x * 128 + (wave & 1) * 64;   // o cols

  f32x4 acc[2][4] = {};

#pragma unroll 4
  for (int k0 = 0; k0 < DIM; k0 += 32) {
    bf16x8 af[2], bf[4];
#pragma unroll
    for (int mi = 0; mi < 2; ++mi)
      af[mi] = *(const bf16x8*)&xb[(size_t)(m0 + mi * 16 + ln) * DIM + k0 + q * 8];
#pragma unroll
    for (int ni = 0; ni < 4; ++ni)
      bf[ni] = *(const bf16x8*)&Mt[(size_t)(n0 + ni * 16 + ln) * DIM + k0 + q * 8];
#pragma unroll
    for (int mi = 0; mi < 2; ++mi)
#pragma unroll
      for (int ni = 0; ni < 4; ++ni)
        acc[mi][ni] = __builtin_amdgcn_mfma_f32_16x16x32_bf16(
            af[mi], bf[ni], acc[mi][ni], 0, 0, 0);
  }

#pragma unroll
  for (int ni = 0; ni < 4; ++ni) {
    const int o = n0 + ni * 16 + ln;
    const float bj = bias[o];
#pragma unroll
    for (int mi = 0; mi < 2; ++mi)
#pragma unroll
      for (int r = 0; r < 4; ++r) {
        const int b = m0 + mi * 16 + q * 4 + r;
        out[(size_t)b * DIM + o] = acc[mi][ni][r] + bj;
      }
  }
}

extern "C" void kernel_launch(void* const* d_in, const int* in_sizes, int n_in,
                              void* d_out, int out_size, void* d_ws, size_t ws_size,
                              hipStream_t stream) {
  const float* x      = (const float*)d_in[0];
  // d_in[1] = adj — irrelevant (softmax rows sum to 1), never read
  const float* w_qkv  = (const float*)d_in[2];
  const float* w_proj = (const float*)d_in[3];
  const float* b_proj = (const float*)d_in[4];
  __bf16* Mt = (__bf16*)d_ws;                          // 512 KB
  __bf16* xb = (__bf16*)((char*)d_ws + DIM * DIM * 2); // 4 MB, 16B-aligned
  float* out = (float*)d_out;                          // 4096*512 fp32

  cvt_x<<<dim3(NNODES * DIM / (256 * 8)), 256, 0, stream>>>(x, xb);
  build_Mt<<<dim3(DIM / 32, DIM / 32), 64, 0, stream>>>(w_qkv, w_proj, Mt);
  gemm_out<<<dim3(DIM / 128, NNODES / 64), 256, 0, stream>>>(xb, Mt, b_proj, out);
}